// Round 16
// baseline (513.480 us; speedup 1.0000x reference)
//
#include <hip/hip_runtime.h>
#include <hip/hip_bf16.h>
#include <hip/hip_fp16.h>

#define N_NODES 50000
#define N_EDGES 400000
#define N_GRAPHS 64
#define HEADS 4
#define GAT_DIM 128
#define FDIM 512   // HEADS*GAT_DIM
#define NEG_SLOPE 0.2f

// R15: packed-fp16 edge math. v/xr/att/accum stay __half2 (v_pk_fma/add, habs2):
// kills all per-edge fp16->fp32 unpack cvts (16/edge) and halves accum ops.
// Softmax STATE stays fp32 (part, mx, denom, scale, w; DPP reduce fp32).
// Kept: dual-sum LK identity (0.6m+0.4|m|), exp2 softmax, DPP 16-lane reduce,
// fp16 hbuf, hierarchical scan, A-reuse MFMA gemm.
#define A6C 0.8656170245333781f   // 0.6 * log2(e)
#define A4C 0.5770780163555854f   // 0.4 * log2(e)
#define L2E 1.4426950408889634f   // log2(e)

#define DPP_ADD(x, ctrl) ((x) + __int_as_float(__builtin_amdgcn_mov_dpp( \
        __float_as_int(x), (ctrl), 0xF, 0xF, true)))

typedef _Float16 f16x8 __attribute__((ext_vector_type(8)));
typedef float f32x4 __attribute__((ext_vector_type(4)));

// ---------------- CSR build ----------------
__global__ void deg_kernel(const int* __restrict__ edst, int* __restrict__ deg) {
    int e = blockIdx.x * blockDim.x + threadIdx.x;
    if (e < N_EDGES) atomicAdd(&deg[edst[e]], 1);
}

// hierarchical exclusive scan: 196 blocks x 256 thr (R14: removed ~80us 1-CU stall)
#define SCB 256
#define SCNB ((N_NODES + SCB - 1) / SCB)   // 196
__global__ __launch_bounds__(SCB) void scan1_kernel(const int* __restrict__ deg,
                                                    int* __restrict__ bsum) {
    __shared__ int sm[SCB];
    int n = blockIdx.x * SCB + threadIdx.x;
    sm[threadIdx.x] = (n < N_NODES) ? deg[n] : 0;
    __syncthreads();
    for (int d = SCB / 2; d > 0; d >>= 1) {
        if (threadIdx.x < d) sm[threadIdx.x] += sm[threadIdx.x + d];
        __syncthreads();
    }
    if (threadIdx.x == 0) bsum[blockIdx.x] = sm[0];
}
__global__ __launch_bounds__(SCB) void scan2_kernel(int* __restrict__ bsum,
                                                    int* __restrict__ off) {
    __shared__ int sm[SCB];
    int t = threadIdx.x;
    int v = (t < SCNB) ? bsum[t] : 0;
    sm[t] = v;
    __syncthreads();
    for (int d = 1; d < SCB; d <<= 1) {
        int add = (t >= d) ? sm[t - d] : 0;
        __syncthreads();
        sm[t] += add;
        __syncthreads();
    }
    if (t < SCNB) bsum[t] = sm[t] - v;           // exclusive block prefix
    if (t == SCNB - 1) off[N_NODES] = sm[t];     // total edges
}
__global__ __launch_bounds__(SCB) void scan3_kernel(const int* __restrict__ deg,
                                                    const int* __restrict__ bsum,
                                                    int* __restrict__ off) {
    __shared__ int sm[SCB];
    int n = blockIdx.x * SCB + threadIdx.x;
    int v = (n < N_NODES) ? deg[n] : 0;
    sm[threadIdx.x] = v;
    __syncthreads();
    for (int d = 1; d < SCB; d <<= 1) {
        int add = (threadIdx.x >= d) ? sm[threadIdx.x - d] : 0;
        __syncthreads();
        sm[threadIdx.x] += add;
        __syncthreads();
    }
    if (n < N_NODES) off[n] = bsum[blockIdx.x] + sm[threadIdx.x] - v;  // exclusive
}

__global__ void fill_kernel(const int* __restrict__ esrc, const int* __restrict__ edst,
                            const int* __restrict__ off, int* __restrict__ cursor,
                            int* __restrict__ csr_src) {
    int e = blockIdx.x * blockDim.x + threadIdx.x;
    if (e >= N_EDGES) return;
    int d = edst[e];
    int pos = off[d] + atomicAdd(&cursor[d], 1);
    csr_src[pos] = esrc[e];
}

// ---------------- weight prep (merged, both layers): Wt[n][k]=concat(Wl,Wr)^T fp16 ----
__global__ __launch_bounds__(128) void wprep_kernel(const float* __restrict__ Wl1,
                                                    const float* __restrict__ Wr1,
                                                    const float* __restrict__ bl1,
                                                    const float* __restrict__ br1,
                                                    const float* __restrict__ Wl2,
                                                    const float* __restrict__ Wr2,
                                                    const float* __restrict__ bl2,
                                                    const float* __restrict__ br2,
                                                    __half* __restrict__ Wt1,
                                                    float* __restrict__ bc1,
                                                    __half* __restrict__ Wt2,
                                                    float* __restrict__ bc2) {
    int b = blockIdx.x;       // 0..2047
    int k = threadIdx.x;      // 0..127
    const float* Wl = (b < 1024) ? Wl1 : Wl2;
    const float* Wr = (b < 1024) ? Wr1 : Wr2;
    const float* bl = (b < 1024) ? bl1 : bl2;
    const float* br = (b < 1024) ? br1 : br2;
    __half* Wt = (b < 1024) ? Wt1 : Wt2;
    float* bc = (b < 1024) ? bc1 : bc2;
    int n = b & 1023;
    float v = (n < 512) ? Wl[(size_t)k * 512 + n] : Wr[(size_t)k * 512 + (n - 512)];
    Wt[(size_t)n * 128 + k] = __float2half(v);
    if (k == 0) bc[n] = (n < 512) ? bl[n] : br[n - 512];
}

// ---------------- fp16 MFMA GEMM, R7 structure + R13 fp16 A ----------------
#define GM 64
#define GP 132
__global__ __launch_bounds__(256) void gemm_mfma_kernel(const __half* __restrict__ A,
                                                        const __half* __restrict__ Wt,
                                                        const float* __restrict__ bc,
                                                        __half* __restrict__ xl,
                                                        __half* __restrict__ xr, int M) {
    __shared__ __align__(16) _Float16 As[GM * GP];     // [m][k] fp16, staged once
    __shared__ __align__(16) _Float16 Bs[128 * GP];    // [n][k] per col-tile; reused as Cs
    const int bm = blockIdx.x * GM;
    const int tid = threadIdx.x;

#pragma unroll
    for (int i = 0; i < 4; i++) {
        int ci = tid + 256 * i;           // 0..1023 16B-chunks
        int r = ci >> 4;                  // 0..63
        int k8 = (ci & 15) * 8;
        int gr = bm + r;
        f16x8 v;
        if (gr < M) {
            v = *(const f16x8*)(A + (size_t)gr * 128 + k8);
        } else {
            v = (f16x8){(_Float16)0, (_Float16)0, (_Float16)0, (_Float16)0,
                        (_Float16)0, (_Float16)0, (_Float16)0, (_Float16)0};
        }
        *(f16x8*)&As[r * GP + k8] = v;
    }

    const int wid = tid >> 6, lane = tid & 63;
    const int wm = wid & 1, wn = wid >> 1;     // wave: m = wm*32.., n = wn*64..
    const int lm = lane & 15;
    const int lk = (lane >> 4) * 8;
    const int lr4 = (lane >> 4) * 4;

    for (int cb = 0; cb < 8; cb++) {
        __syncthreads();   // cb=0: As visible; cb>0: prior store-loop's Cs reads done
#pragma unroll
        for (int i = 0; i < 8; i++) {
            int ci = tid + 256 * i;       // 0..2047 16B-chunks
            int r = ci >> 4;              // 0..127
            int k8 = (ci & 15) * 8;
            *(f16x8*)&Bs[r * GP + k8] =
                *(const f16x8*)(Wt + ((size_t)(cb * 128 + r)) * 128 + k8);
        }
        __syncthreads();

        f32x4 acc[4][2];
#pragma unroll
        for (int fn = 0; fn < 4; fn++)
#pragma unroll
            for (int fm = 0; fm < 2; fm++) acc[fn][fm] = (f32x4){0.f, 0.f, 0.f, 0.f};

#pragma unroll
        for (int ks = 0; ks < 4; ks++) {
            f16x8 af[4], bf[2];
#pragma unroll
            for (int fn = 0; fn < 4; fn++)
                af[fn] = *(const f16x8*)&Bs[(wn * 64 + fn * 16 + lm) * GP + ks * 32 + lk];
#pragma unroll
            for (int fm = 0; fm < 2; fm++)
                bf[fm] = *(const f16x8*)&As[(wm * 32 + fm * 16 + lm) * GP + ks * 32 + lk];
#pragma unroll
            for (int fn = 0; fn < 4; fn++)
#pragma unroll
                for (int fm = 0; fm < 2; fm++)
                    acc[fn][fm] = __builtin_amdgcn_mfma_f32_16x16x32_f16(af[fn], bf[fm],
                                                                         acc[fn][fm], 0, 0, 0);
        }
        __syncthreads();   // all Bs fragment reads complete

        _Float16* Cs = Bs;
#pragma unroll
        for (int fn = 0; fn < 4; fn++) {
            float4 b4 = *(const float4*)(bc + cb * 128 + wn * 64 + fn * 16 + lr4);
#pragma unroll
            for (int fm = 0; fm < 2; fm++) {
                f32x4 v = acc[fn][fm];
                union { _Float16 h[4]; float2 f2; } u;
                u.h[0] = (_Float16)(v[0] + b4.x);
                u.h[1] = (_Float16)(v[1] + b4.y);
                u.h[2] = (_Float16)(v[2] + b4.z);
                u.h[3] = (_Float16)(v[3] + b4.w);
                int m_loc = wm * 32 + fm * 16 + lm;
                int n_loc = wn * 64 + fn * 16 + lr4;
                *(float2*)&Cs[m_loc * GP + n_loc] = u.f2;
            }
        }
        __syncthreads();

        __half* dst = (cb < 4) ? xl : xr;
        const int c0 = (cb & 3) * 128;
#pragma unroll
        for (int i = 0; i < 4; i++) {
            int ci = tid + 256 * i;       // 0..1023 16B-chunks
            int r = ci >> 4;              // 0..63
            int c8 = (ci & 15) * 8;
            int gr = bm + r;
            if (gr < M) {
                float4 v = *(const float4*)&Cs[r * GP + c8];
                *(float4*)(dst + (size_t)gr * 512 + c0 + c8) = v;
            }
        }
    }
}

// ------- LAYER 0, R15: fp32 transform -> pk-fp16 score/accum + DPP + exp2 -------
#define EW0_BLOCKS 2048
#define EW0_NW (EW0_BLOCKS * 4)
__global__ __launch_bounds__(256) void fused_edge0_kernel(const int* __restrict__ off,
                                                          const int* __restrict__ csr_src,
                                                          const float* __restrict__ x,
                                                          const float* __restrict__ Wl,
                                                          const float* __restrict__ bl,
                                                          const float* __restrict__ Wr,
                                                          const float* __restrict__ br,
                                                          const float* __restrict__ att,
                                                          const float* __restrict__ bias,
                                                          __half* __restrict__ hout) {
    const int lane = threadIdx.x & 63;
    const int wglob = blockIdx.x * 4 + (threadIdx.x >> 6);
    const int loff = lane * 8;
    float4 wl00 = *(const float4*)(Wl + loff),        wl01 = *(const float4*)(Wl + loff + 4);
    float4 wl10 = *(const float4*)(Wl + 512 + loff),  wl11 = *(const float4*)(Wl + 512 + loff + 4);
    float4 wl20 = *(const float4*)(Wl + 1024 + loff), wl21 = *(const float4*)(Wl + 1024 + loff + 4);
    float4 bl0  = *(const float4*)(bl + loff),        bl1  = *(const float4*)(bl + loff + 4);
    __half2 ath[4];
    {
        float4 a0r = *(const float4*)(att + loff);
        float4 a1r = *(const float4*)(att + loff + 4);
        ath[0] = __floats2half2_rn(a0r.x, a0r.y);
        ath[1] = __floats2half2_rn(a0r.z, a0r.w);
        ath[2] = __floats2half2_rn(a1r.x, a1r.y);
        ath[3] = __floats2half2_rn(a1r.z, a1r.w);
    }
    float4 wr00 = *(const float4*)(Wr + loff),        wr01 = *(const float4*)(Wr + loff + 4);
    float4 wr10 = *(const float4*)(Wr + 512 + loff),  wr11 = *(const float4*)(Wr + 512 + loff + 4);
    float4 wr20 = *(const float4*)(Wr + 1024 + loff), wr21 = *(const float4*)(Wr + 1024 + loff + 4);
    float4 br0  = *(const float4*)(br + loff),        br1  = *(const float4*)(br + loff + 4);

    for (int n = wglob; n < N_NODES; n += EW0_NW) {
        int s = off[n], e = off[n + 1];
        float xn0 = x[n * 3 + 0], xn1 = x[n * 3 + 1], xn2 = x[n * 3 + 2];
        __half2 xrh[4];
        {
            float4 xr0, xr1;
            xr0.x = fmaf(xn0, wr00.x, fmaf(xn1, wr10.x, fmaf(xn2, wr20.x, br0.x)));
            xr0.y = fmaf(xn0, wr00.y, fmaf(xn1, wr10.y, fmaf(xn2, wr20.y, br0.y)));
            xr0.z = fmaf(xn0, wr00.z, fmaf(xn1, wr10.z, fmaf(xn2, wr20.z, br0.z)));
            xr0.w = fmaf(xn0, wr00.w, fmaf(xn1, wr10.w, fmaf(xn2, wr20.w, br0.w)));
            xr1.x = fmaf(xn0, wr01.x, fmaf(xn1, wr11.x, fmaf(xn2, wr21.x, br1.x)));
            xr1.y = fmaf(xn0, wr01.y, fmaf(xn1, wr11.y, fmaf(xn2, wr21.y, br1.y)));
            xr1.z = fmaf(xn0, wr01.z, fmaf(xn1, wr11.z, fmaf(xn2, wr21.z, br1.z)));
            xr1.w = fmaf(xn0, wr01.w, fmaf(xn1, wr11.w, fmaf(xn2, wr21.w, br1.w)));
            xrh[0] = __floats2half2_rn(xr0.x, xr0.y);
            xrh[1] = __floats2half2_rn(xr0.z, xr0.w);
            xrh[2] = __floats2half2_rn(xr1.x, xr1.y);
            xrh[3] = __floats2half2_rn(xr1.z, xr1.w);
        }

        float mx = -1e30f, denom = 0.f;
        __half2 ah0 = __floats2half2_rn(0.f, 0.f);
        __half2 ah1 = ah0, ah2 = ah0, ah3 = ah0;

        float c0, c1, c2, n0, n1, n2;
        if (s < e) { int i0 = csr_src[s]; c0 = x[i0 * 3]; c1 = x[i0 * 3 + 1]; c2 = x[i0 * 3 + 2]; }
        if (s + 1 < e) { int i1 = csr_src[s + 1]; n0 = x[i1 * 3]; n1 = x[i1 * 3 + 1]; n2 = x[i1 * 3 + 2]; }
        for (int p = s; p < e; p++) {
            float t0, t1, t2;
            if (p + 2 < e) {
                int i2 = csr_src[p + 2];
                t0 = x[i2 * 3]; t1 = x[i2 * 3 + 1]; t2 = x[i2 * 3 + 2];
            }
            float4 v0, v1;
            v0.x = fmaf(c0, wl00.x, fmaf(c1, wl10.x, fmaf(c2, wl20.x, bl0.x)));
            v0.y = fmaf(c0, wl00.y, fmaf(c1, wl10.y, fmaf(c2, wl20.y, bl0.y)));
            v0.z = fmaf(c0, wl00.z, fmaf(c1, wl10.z, fmaf(c2, wl20.z, bl0.z)));
            v0.w = fmaf(c0, wl00.w, fmaf(c1, wl10.w, fmaf(c2, wl20.w, bl0.w)));
            v1.x = fmaf(c0, wl01.x, fmaf(c1, wl11.x, fmaf(c2, wl21.x, bl1.x)));
            v1.y = fmaf(c0, wl01.y, fmaf(c1, wl11.y, fmaf(c2, wl21.y, bl1.y)));
            v1.z = fmaf(c0, wl01.z, fmaf(c1, wl11.z, fmaf(c2, wl21.z, bl1.z)));
            v1.w = fmaf(c0, wl01.w, fmaf(c1, wl11.w, fmaf(c2, wl21.w, bl1.w)));
            __half2 vh0 = __floats2half2_rn(v0.x, v0.y);
            __half2 vh1 = __floats2half2_rn(v0.z, v0.w);
            __half2 vh2 = __floats2half2_rn(v1.x, v1.y);
            __half2 vh3 = __floats2half2_rn(v1.z, v1.w);
            __half2 mm0 = __hadd2(vh0, xrh[0]);
            __half2 mm1 = __hadd2(vh1, xrh[1]);
            __half2 mm2 = __hadd2(vh2, xrh[2]);
            __half2 mm3 = __hadd2(vh3, xrh[3]);
            __half2 s1h = __hmul2(ath[0], mm0);
            s1h = __hfma2(ath[1], mm1, s1h);
            s1h = __hfma2(ath[2], mm2, s1h);
            s1h = __hfma2(ath[3], mm3, s1h);
            __half2 s2h = __hmul2(ath[0], __habs2(mm0));
            s2h = __hfma2(ath[1], __habs2(mm1), s2h);
            s2h = __hfma2(ath[2], __habs2(mm2), s2h);
            s2h = __hfma2(ath[3], __habs2(mm3), s2h);
            float s1 = __low2float(s1h) + __high2float(s1h);
            float s2 = __low2float(s2h) + __high2float(s2h);
            float part = fmaf(A6C, s1, A4C * s2);
            part = DPP_ADD(part, 0xB1);   // quad_perm [1,0,3,2]  (xor 1)
            part = DPP_ADD(part, 0x4E);   // quad_perm [2,3,0,1]  (xor 2)
            part = DPP_ADD(part, 0x124);  // row_ror:4
            part = DPP_ADD(part, 0x128);  // row_ror:8
            float mnew = fmaxf(mx, part);
            float scale = exp2f(mx - mnew);
            float w = exp2f(part - mnew);
            denom = fmaf(denom, scale, w);
            __half2 w2 = __float2half2_rn(w);
            __half2 sc2 = __float2half2_rn(scale);
            ah0 = __hfma2(ah0, sc2, __hmul2(w2, vh0));
            ah1 = __hfma2(ah1, sc2, __hmul2(w2, vh1));
            ah2 = __hfma2(ah2, sc2, __hmul2(w2, vh2));
            ah3 = __hfma2(ah3, sc2, __hmul2(w2, vh3));
            mx = mnew;
            c0 = n0; c1 = n1; c2 = n2;
            n0 = t0; n1 = t1; n2 = t2;
        }
        float inv = denom > 0.f ? 1.f / denom : 0.f;
        float a0 = __low2float(ah0) * inv, a1 = __high2float(ah0) * inv;
        float a2 = __low2float(ah1) * inv, a3 = __high2float(ah1) * inv;
        float a4 = __low2float(ah2) * inv, a5 = __high2float(ah2) * inv;
        float a6 = __low2float(ah3) * inv, a7 = __high2float(ah3) * inv;
        a0 += __shfl_xor(a0, 16); a0 += __shfl_xor(a0, 32);
        a1 += __shfl_xor(a1, 16); a1 += __shfl_xor(a1, 32);
        a2 += __shfl_xor(a2, 16); a2 += __shfl_xor(a2, 32);
        a3 += __shfl_xor(a3, 16); a3 += __shfl_xor(a3, 32);
        a4 += __shfl_xor(a4, 16); a4 += __shfl_xor(a4, 32);
        a5 += __shfl_xor(a5, 16); a5 += __shfl_xor(a5, 32);
        a6 += __shfl_xor(a6, 16); a6 += __shfl_xor(a6, 32);
        a7 += __shfl_xor(a7, 16); a7 += __shfl_xor(a7, 32);
        if (lane < 16) {
            float4 b0 = *(const float4*)(bias + lane * 8);
            float4 b1 = *(const float4*)(bias + lane * 8 + 4);
            float o[8];
            o[0] = fmaf(0.25f, a0, b0.x); o[1] = fmaf(0.25f, a1, b0.y);
            o[2] = fmaf(0.25f, a2, b0.z); o[3] = fmaf(0.25f, a3, b0.w);
            o[4] = fmaf(0.25f, a4, b1.x); o[5] = fmaf(0.25f, a5, b1.y);
            o[6] = fmaf(0.25f, a6, b1.z); o[7] = fmaf(0.25f, a7, b1.w);
#pragma unroll
            for (int j = 0; j < 8; j++) o[j] = o[j] > 0.f ? o[j] : (exp2f(o[j] * L2E) - 1.f);
            union { __half2 h2[4]; float4 f4; } u;
            u.h2[0] = __float22half2_rn(make_float2(o[0], o[1]));
            u.h2[1] = __float22half2_rn(make_float2(o[2], o[3]));
            u.h2[2] = __float22half2_rn(make_float2(o[4], o[5]));
            u.h2[3] = __float22half2_rn(make_float2(o[6], o[7]));
            *(float4*)(hout + (size_t)n * GAT_DIM + lane * 8) = u.f4;
        }
    }
}

// ------- layers 1/2, R15: native pk-fp16 score/accum (zero unpack cvts) --------
__global__ __launch_bounds__(256) void fused_edge_kernel(const int* __restrict__ off,
                                                         const int* __restrict__ csr_src,
                                                         const __half* __restrict__ xl,
                                                         const __half* __restrict__ xr,
                                                         const float* __restrict__ att,
                                                         const float* __restrict__ bias,
                                                         __half* __restrict__ hout) {
    int wid = threadIdx.x >> 6;
    int lane = threadIdx.x & 63;
    int n = blockIdx.x * 4 + wid;
    if (n >= N_NODES) return;
    int s = off[n], e = off[n + 1];
    const int loff = lane * 8;
    __half2 xrh[4];
    {
        float4 rxr = *(const float4*)(xr + (size_t)n * FDIM + loff);
        const __half2* xp = (const __half2*)&rxr;
        xrh[0] = xp[0]; xrh[1] = xp[1]; xrh[2] = xp[2]; xrh[3] = xp[3];
    }
    __half2 ath[4];
    {
        float4 a0r = *(const float4*)(att + loff);
        float4 a1r = *(const float4*)(att + loff + 4);
        ath[0] = __floats2half2_rn(a0r.x, a0r.y);
        ath[1] = __floats2half2_rn(a0r.z, a0r.w);
        ath[2] = __floats2half2_rn(a1r.x, a1r.y);
        ath[3] = __floats2half2_rn(a1r.z, a1r.w);
    }

    float mx = -1e30f, denom = 0.f;
    __half2 ah0 = __floats2half2_rn(0.f, 0.f);
    __half2 ah1 = ah0, ah2 = ah0, ah3 = ah0;

    float4 rcur, rnext;
    if (s < e)     rcur  = *(const float4*)(xl + (size_t)csr_src[s] * FDIM + loff);
    if (s + 1 < e) rnext = *(const float4*)(xl + (size_t)csr_src[s + 1] * FDIM + loff);
    for (int p = s; p < e; p++) {
        float4 rt;
        if (p + 2 < e) rt = *(const float4*)(xl + (size_t)csr_src[p + 2] * FDIM + loff);
        const __half2* vh = (const __half2*)&rcur;
        __half2 mm0 = __hadd2(vh[0], xrh[0]);
        __half2 mm1 = __hadd2(vh[1], xrh[1]);
        __half2 mm2 = __hadd2(vh[2], xrh[2]);
        __half2 mm3 = __hadd2(vh[3], xrh[3]);
        __half2 s1h = __hmul2(ath[0], mm0);
        s1h = __hfma2(ath[1], mm1, s1h);
        s1h = __hfma2(ath[2], mm2, s1h);
        s1h = __hfma2(ath[3], mm3, s1h);
        __half2 s2h = __hmul2(ath[0], __habs2(mm0));
        s2h = __hfma2(ath[1], __habs2(mm1), s2h);
        s2h = __hfma2(ath[2], __habs2(mm2), s2h);
        s2h = __hfma2(ath[3], __habs2(mm3), s2h);
        float s1 = __low2float(s1h) + __high2float(s1h);
        float s2 = __low2float(s2h) + __high2float(s2h);
        float part = fmaf(A6C, s1, A4C * s2);
        part = DPP_ADD(part, 0xB1);   // xor 1
        part = DPP_ADD(part, 0x4E);   // xor 2
        part = DPP_ADD(part, 0x124);  // row_ror:4
        part = DPP_ADD(part, 0x128);  // row_ror:8
        float mnew = fmaxf(mx, part);
        float scale = exp2f(mx - mnew);
        float w = exp2f(part - mnew);
        denom = fmaf(denom, scale, w);
        __half2 w2 = __float2half2_rn(w);
        __half2 sc2 = __float2half2_rn(scale);
        ah0 = __hfma2(ah0, sc2, __hmul2(w2, vh[0]));
        ah1 = __hfma2(ah1, sc2, __hmul2(w2, vh[1]));
        ah2 = __hfma2(ah2, sc2, __hmul2(w2, vh[2]));
        ah3 = __hfma2(ah3, sc2, __hmul2(w2, vh[3]));
        mx = mnew;
        rcur = rnext;
        rnext = rt;
    }
    float inv = denom > 0.f ? 1.f / denom : 0.f;
    float a0 = __low2float(ah0) * inv, a1 = __high2float(ah0) * inv;
    float a2 = __low2float(ah1) * inv, a3 = __high2float(ah1) * inv;
    float a4 = __low2float(ah2) * inv, a5 = __high2float(ah2) * inv;
    float a6 = __low2float(ah3) * inv, a7 = __high2float(ah3) * inv;
    a0 += __shfl_xor(a0, 16); a0 += __shfl_xor(a0, 32);
    a1 += __shfl_xor(a1, 16); a1 += __shfl_xor(a1, 32);
    a2 += __shfl_xor(a2, 16); a2 += __shfl_xor(a2, 32);
    a3 += __shfl_xor(a3, 16); a3 += __shfl_xor(a3, 32);
    a4 += __shfl_xor(a4, 16); a4 += __shfl_xor(a4, 32);
    a5 += __shfl_xor(a5, 16); a5 += __shfl_xor(a5, 32);
    a6 += __shfl_xor(a6, 16); a6 += __shfl_xor(a6, 32);
    a7 += __shfl_xor(a7, 16); a7 += __shfl_xor(a7, 32);
    if (lane < 16) {
        float4 b0 = *(const float4*)(bias + lane * 8);
        float4 b1 = *(const float4*)(bias + lane * 8 + 4);
        float o[8];
        o[0] = fmaf(0.25f, a0, b0.x); o[1] = fmaf(0.25f, a1, b0.y);
        o[2] = fmaf(0.25f, a2, b0.z); o[3] = fmaf(0.25f, a3, b0.w);
        o[4] = fmaf(0.25f, a4, b1.x); o[5] = fmaf(0.25f, a5, b1.y);
        o[6] = fmaf(0.25f, a6, b1.z); o[7] = fmaf(0.25f, a7, b1.w);
#pragma unroll
        for (int j = 0; j < 8; j++) o[j] = o[j] > 0.f ? o[j] : (exp2f(o[j] * L2E) - 1.f);
        union { __half2 h2[4]; float4 f4; } u;
        u.h2[0] = __float22half2_rn(make_float2(o[0], o[1]));
        u.h2[1] = __float22half2_rn(make_float2(o[2], o[3]));
        u.h2[2] = __float22half2_rn(make_float2(o[4], o[5]));
        u.h2[3] = __float22half2_rn(make_float2(o[6], o[7]));
        *(float4*)(hout + (size_t)n * GAT_DIM + lane * 8) = u.f4;
    }
}

// ---------------- mean pool over sorted batch (fp16 in, double accumulation) ------------
#define POOL_CHUNK 64
__global__ __launch_bounds__(128) void pool_kernel(const __half* __restrict__ h,
                                                   const int* __restrict__ batch,
                                                   double* __restrict__ psum,
                                                   int* __restrict__ pcnt) {
    int c = threadIdx.x;  // 0..127
    int n0 = blockIdx.x * POOL_CHUNK;
    int n1 = min(n0 + POOL_CHUNK, N_NODES);
    if (n0 >= N_NODES) return;
    double acc = 0.0;
    int cur = batch[n0];
    int cnt = 0;
    for (int n = n0; n < n1; n++) {
        int g = batch[n];
        if (g != cur) {
            atomicAdd(&psum[(size_t)cur * GAT_DIM + c], acc);
            if (c == 0) atomicAdd(&pcnt[cur], cnt);
            acc = 0.0; cnt = 0; cur = g;
        }
        acc += (double)__half2float(h[(size_t)n * GAT_DIM + c]);
        cnt++;
    }
    atomicAdd(&psum[(size_t)cur * GAT_DIM + c], acc);
    if (c == 0) atomicAdd(&pcnt[cur], cnt);
}

// ---------------- final linear: out[64,128] = g @ linW + linb ----------------
__global__ __launch_bounds__(128) void final_kernel(const double* __restrict__ psum,
                                                    const int* __restrict__ pcnt,
                                                    const float* __restrict__ linW,
                                                    const float* __restrict__ linb,
                                                    float* __restrict__ out) {
    int g = blockIdx.x;       // 0..63
    int j = threadIdx.x;      // 0..127
    __shared__ float gv[128];
    float cnt = (float)max(pcnt[g], 1);
    gv[j] = (float)(psum[(size_t)g * 128 + j] / (double)cnt);
    __syncthreads();
    float acc = 0.f;
    for (int c = 0; c < 128; c++) acc = fmaf(gv[c], linW[c * 128 + j], acc);
    out[(size_t)g * 128 + j] = acc + linb[j];
}

extern "C" void kernel_launch(void* const* d_in, const int* in_sizes, int n_in,
                              void* d_out, int out_size, void* d_ws, size_t ws_size,
                              hipStream_t stream) {
    const float* x    = (const float*)d_in[0];
    const int* eidx   = (const int*)d_in[1];
    const int* batch  = (const int*)d_in[2];
    const float* Wl[3] = {(const float*)d_in[3],  (const float*)d_in[9],  (const float*)d_in[15]};
    const float* bl[3] = {(const float*)d_in[4],  (const float*)d_in[10], (const float*)d_in[16]};
    const float* Wr[3] = {(const float*)d_in[5],  (const float*)d_in[11], (const float*)d_in[17]};
    const float* br[3] = {(const float*)d_in[6],  (const float*)d_in[12], (const float*)d_in[18]};
    const float* att[3] = {(const float*)d_in[7], (const float*)d_in[13], (const float*)d_in[19]};
    const float* bb[3] = {(const float*)d_in[8],  (const float*)d_in[14], (const float*)d_in[20]};
    const float* linW = (const float*)d_in[21];
    const float* linb = (const float*)d_in[22];
    float* out = (float*)d_out;

    const int* esrc = eidx;
    const int* edst = eidx + N_EDGES;

    // workspace carve-up (256B aligned)
    char* p = (char*)d_ws;
    auto alloc = [&](size_t bytes) { void* r = (void*)p; p += (bytes + 255) & ~(size_t)255; return r; };
    __half* xl     = (__half*)alloc((size_t)N_NODES * FDIM * 2);  // 51.2 MB (fp16)
    __half* xr     = (__half*)alloc((size_t)N_NODES * FDIM * 2);  // 51.2 MB (fp16)
    __half* hbuf   = (__half*)alloc((size_t)N_NODES * GAT_DIM * 2);// 12.8 MB (fp16)
    int*   off     = (int*)alloc((size_t)(N_NODES + 1) * 4);
    int*   csr_src = (int*)alloc((size_t)N_EDGES * 4);
    int*   bsum    = (int*)alloc((size_t)SCNB * 4);
    __half* Wt1    = (__half*)alloc((size_t)1024 * 128 * 2);
    __half* Wt2    = (__half*)alloc((size_t)1024 * 128 * 2);
    float* bc1     = (float*)alloc((size_t)1024 * 4);
    float* bc2     = (float*)alloc((size_t)1024 * 4);
    // --- contiguous zero region: deg, cursor, psum, pcnt ---
    char* zbase = p;
    int*   deg     = (int*)alloc((size_t)N_NODES * 4);
    int*   cursor  = (int*)alloc((size_t)N_NODES * 4);
    double* psum   = (double*)alloc((size_t)N_GRAPHS * GAT_DIM * 8);
    int*   pcnt    = (int*)alloc((size_t)N_GRAPHS * 4);
    size_t zbytes = (size_t)(p - zbase);

    hipMemsetAsync(zbase, 0, zbytes, stream);

    // CSR build (hierarchical scan) + merged weight prep
    deg_kernel<<<(N_EDGES + 255) / 256, 256, 0, stream>>>(edst, deg);
    scan1_kernel<<<SCNB, SCB, 0, stream>>>(deg, bsum);
    scan2_kernel<<<1, SCB, 0, stream>>>(bsum, off);
    scan3_kernel<<<SCNB, SCB, 0, stream>>>(deg, bsum, off);
    fill_kernel<<<(N_EDGES + 255) / 256, 256, 0, stream>>>(esrc, edst, off, cursor, csr_src);
    wprep_kernel<<<2048, 128, 0, stream>>>(Wl[1], Wr[1], bl[1], br[1],
                                           Wl[2], Wr[2], bl[2], br[2],
                                           Wt1, bc1, Wt2, bc2);

    const int ggrid = (N_NODES + GM - 1) / GM;   // 782 blocks, each loops 8 col tiles
    const int egrid = (N_NODES + 3) / 4;         // 4 nodes (waves) per 256-thr block

    // layer 0: fully fused (K=3 transform recomputed per edge), persistent waves
    fused_edge0_kernel<<<EW0_BLOCKS, 256, 0, stream>>>(off, csr_src, x, Wl[0], bl[0],
                                                       Wr[0], br[0], att[0], bb[0], hbuf);
    // layers 1,2
    __half* Wt[3] = {nullptr, Wt1, Wt2};
    float*  bc[3] = {nullptr, bc1, bc2};
    for (int l = 1; l < 3; l++) {
        gemm_mfma_kernel<<<ggrid, 256, 0, stream>>>(hbuf, Wt[l], bc[l], xl, xr, N_NODES);
        fused_edge_kernel<<<egrid, 256, 0, stream>>>(off, csr_src, xl, xr,
                                                     att[l], bb[l], hbuf);
    }

    pool_kernel<<<(N_NODES + POOL_CHUNK - 1) / POOL_CHUNK, 128, 0, stream>>>(hbuf, batch, psum, pcnt);
    final_kernel<<<N_GRAPHS, 128, 0, stream>>>(psum, pcnt, linW, linb, out);
}

// Round 17
// 509.024 us; speedup vs baseline: 1.0088x; 1.0088x over previous
//
#include <hip/hip_runtime.h>
#include <hip/hip_bf16.h>
#include <hip/hip_fp16.h>

#define N_NODES 50000
#define N_EDGES 400000
#define N_GRAPHS 64
#define HEADS 4
#define GAT_DIM 128
#define FDIM 512   // HEADS*GAT_DIM
#define NEG_SLOPE 0.2f

// R16 hybrid (post R15 A/B): edge0 = R14 fp32 score path (fp32-born transform; pk
// packing cost > savings there — R15: 111->117.5). fused_edge = R15 pk-fp16 path
// (fp16-born gather; zero pack cost, removes 16 unpack cvts/edge).
// Shared: dual-sum LK identity (0.6m+0.4|m|), exp2 softmax, DPP 16-lane reduce,
// fp16 hbuf/xl/xr, hierarchical scan, A-reuse MFMA gemm.
#define A6C 0.8656170245333781f   // 0.6 * log2(e)
#define A4C 0.5770780163555854f   // 0.4 * log2(e)
#define L2E 1.4426950408889634f   // log2(e)

#define DPP_ADD(x, ctrl) ((x) + __int_as_float(__builtin_amdgcn_mov_dpp( \
        __float_as_int(x), (ctrl), 0xF, 0xF, true)))

typedef _Float16 f16x8 __attribute__((ext_vector_type(8)));
typedef float f32x4 __attribute__((ext_vector_type(4)));

// ---------------- CSR build ----------------
__global__ void deg_kernel(const int* __restrict__ edst, int* __restrict__ deg) {
    int e = blockIdx.x * blockDim.x + threadIdx.x;
    if (e < N_EDGES) atomicAdd(&deg[edst[e]], 1);
}

// hierarchical exclusive scan: 196 blocks x 256 thr (R14: removed ~80us 1-CU stall)
#define SCB 256
#define SCNB ((N_NODES + SCB - 1) / SCB)   // 196
__global__ __launch_bounds__(SCB) void scan1_kernel(const int* __restrict__ deg,
                                                    int* __restrict__ bsum) {
    __shared__ int sm[SCB];
    int n = blockIdx.x * SCB + threadIdx.x;
    sm[threadIdx.x] = (n < N_NODES) ? deg[n] : 0;
    __syncthreads();
    for (int d = SCB / 2; d > 0; d >>= 1) {
        if (threadIdx.x < d) sm[threadIdx.x] += sm[threadIdx.x + d];
        __syncthreads();
    }
    if (threadIdx.x == 0) bsum[blockIdx.x] = sm[0];
}
__global__ __launch_bounds__(SCB) void scan2_kernel(int* __restrict__ bsum,
                                                    int* __restrict__ off) {
    __shared__ int sm[SCB];
    int t = threadIdx.x;
    int v = (t < SCNB) ? bsum[t] : 0;
    sm[t] = v;
    __syncthreads();
    for (int d = 1; d < SCB; d <<= 1) {
        int add = (t >= d) ? sm[t - d] : 0;
        __syncthreads();
        sm[t] += add;
        __syncthreads();
    }
    if (t < SCNB) bsum[t] = sm[t] - v;           // exclusive block prefix
    if (t == SCNB - 1) off[N_NODES] = sm[t];     // total edges
}
__global__ __launch_bounds__(SCB) void scan3_kernel(const int* __restrict__ deg,
                                                    const int* __restrict__ bsum,
                                                    int* __restrict__ off) {
    __shared__ int sm[SCB];
    int n = blockIdx.x * SCB + threadIdx.x;
    int v = (n < N_NODES) ? deg[n] : 0;
    sm[threadIdx.x] = v;
    __syncthreads();
    for (int d = 1; d < SCB; d <<= 1) {
        int add = (threadIdx.x >= d) ? sm[threadIdx.x - d] : 0;
        __syncthreads();
        sm[threadIdx.x] += add;
        __syncthreads();
    }
    if (n < N_NODES) off[n] = bsum[blockIdx.x] + sm[threadIdx.x] - v;  // exclusive
}

__global__ void fill_kernel(const int* __restrict__ esrc, const int* __restrict__ edst,
                            const int* __restrict__ off, int* __restrict__ cursor,
                            int* __restrict__ csr_src) {
    int e = blockIdx.x * blockDim.x + threadIdx.x;
    if (e >= N_EDGES) return;
    int d = edst[e];
    int pos = off[d] + atomicAdd(&cursor[d], 1);
    csr_src[pos] = esrc[e];
}

// ---------------- weight prep (merged, both layers): Wt[n][k]=concat(Wl,Wr)^T fp16 ----
__global__ __launch_bounds__(128) void wprep_kernel(const float* __restrict__ Wl1,
                                                    const float* __restrict__ Wr1,
                                                    const float* __restrict__ bl1,
                                                    const float* __restrict__ br1,
                                                    const float* __restrict__ Wl2,
                                                    const float* __restrict__ Wr2,
                                                    const float* __restrict__ bl2,
                                                    const float* __restrict__ br2,
                                                    __half* __restrict__ Wt1,
                                                    float* __restrict__ bc1,
                                                    __half* __restrict__ Wt2,
                                                    float* __restrict__ bc2) {
    int b = blockIdx.x;       // 0..2047
    int k = threadIdx.x;      // 0..127
    const float* Wl = (b < 1024) ? Wl1 : Wl2;
    const float* Wr = (b < 1024) ? Wr1 : Wr2;
    const float* bl = (b < 1024) ? bl1 : bl2;
    const float* br = (b < 1024) ? br1 : br2;
    __half* Wt = (b < 1024) ? Wt1 : Wt2;
    float* bc = (b < 1024) ? bc1 : bc2;
    int n = b & 1023;
    float v = (n < 512) ? Wl[(size_t)k * 512 + n] : Wr[(size_t)k * 512 + (n - 512)];
    Wt[(size_t)n * 128 + k] = __float2half(v);
    if (k == 0) bc[n] = (n < 512) ? bl[n] : br[n - 512];
}

// ---------------- fp16 MFMA GEMM, R7 structure + R13 fp16 A ----------------
#define GM 64
#define GP 132
__global__ __launch_bounds__(256) void gemm_mfma_kernel(const __half* __restrict__ A,
                                                        const __half* __restrict__ Wt,
                                                        const float* __restrict__ bc,
                                                        __half* __restrict__ xl,
                                                        __half* __restrict__ xr, int M) {
    __shared__ __align__(16) _Float16 As[GM * GP];     // [m][k] fp16, staged once
    __shared__ __align__(16) _Float16 Bs[128 * GP];    // [n][k] per col-tile; reused as Cs
    const int bm = blockIdx.x * GM;
    const int tid = threadIdx.x;

#pragma unroll
    for (int i = 0; i < 4; i++) {
        int ci = tid + 256 * i;           // 0..1023 16B-chunks
        int r = ci >> 4;                  // 0..63
        int k8 = (ci & 15) * 8;
        int gr = bm + r;
        f16x8 v;
        if (gr < M) {
            v = *(const f16x8*)(A + (size_t)gr * 128 + k8);
        } else {
            v = (f16x8){(_Float16)0, (_Float16)0, (_Float16)0, (_Float16)0,
                        (_Float16)0, (_Float16)0, (_Float16)0, (_Float16)0};
        }
        *(f16x8*)&As[r * GP + k8] = v;
    }

    const int wid = tid >> 6, lane = tid & 63;
    const int wm = wid & 1, wn = wid >> 1;     // wave: m = wm*32.., n = wn*64..
    const int lm = lane & 15;
    const int lk = (lane >> 4) * 8;
    const int lr4 = (lane >> 4) * 4;

    for (int cb = 0; cb < 8; cb++) {
        __syncthreads();   // cb=0: As visible; cb>0: prior store-loop's Cs reads done
#pragma unroll
        for (int i = 0; i < 8; i++) {
            int ci = tid + 256 * i;       // 0..2047 16B-chunks
            int r = ci >> 4;              // 0..127
            int k8 = (ci & 15) * 8;
            *(f16x8*)&Bs[r * GP + k8] =
                *(const f16x8*)(Wt + ((size_t)(cb * 128 + r)) * 128 + k8);
        }
        __syncthreads();

        f32x4 acc[4][2];
#pragma unroll
        for (int fn = 0; fn < 4; fn++)
#pragma unroll
            for (int fm = 0; fm < 2; fm++) acc[fn][fm] = (f32x4){0.f, 0.f, 0.f, 0.f};

#pragma unroll
        for (int ks = 0; ks < 4; ks++) {
            f16x8 af[4], bf[2];
#pragma unroll
            for (int fn = 0; fn < 4; fn++)
                af[fn] = *(const f16x8*)&Bs[(wn * 64 + fn * 16 + lm) * GP + ks * 32 + lk];
#pragma unroll
            for (int fm = 0; fm < 2; fm++)
                bf[fm] = *(const f16x8*)&As[(wm * 32 + fm * 16 + lm) * GP + ks * 32 + lk];
#pragma unroll
            for (int fn = 0; fn < 4; fn++)
#pragma unroll
                for (int fm = 0; fm < 2; fm++)
                    acc[fn][fm] = __builtin_amdgcn_mfma_f32_16x16x32_f16(af[fn], bf[fm],
                                                                         acc[fn][fm], 0, 0, 0);
        }
        __syncthreads();   // all Bs fragment reads complete

        _Float16* Cs = Bs;
#pragma unroll
        for (int fn = 0; fn < 4; fn++) {
            float4 b4 = *(const float4*)(bc + cb * 128 + wn * 64 + fn * 16 + lr4);
#pragma unroll
            for (int fm = 0; fm < 2; fm++) {
                f32x4 v = acc[fn][fm];
                union { _Float16 h[4]; float2 f2; } u;
                u.h[0] = (_Float16)(v[0] + b4.x);
                u.h[1] = (_Float16)(v[1] + b4.y);
                u.h[2] = (_Float16)(v[2] + b4.z);
                u.h[3] = (_Float16)(v[3] + b4.w);
                int m_loc = wm * 32 + fm * 16 + lm;
                int n_loc = wn * 64 + fn * 16 + lr4;
                *(float2*)&Cs[m_loc * GP + n_loc] = u.f2;
            }
        }
        __syncthreads();

        __half* dst = (cb < 4) ? xl : xr;
        const int c0 = (cb & 3) * 128;
#pragma unroll
        for (int i = 0; i < 4; i++) {
            int ci = tid + 256 * i;       // 0..1023 16B-chunks
            int r = ci >> 4;              // 0..63
            int c8 = (ci & 15) * 8;
            int gr = bm + r;
            if (gr < M) {
                float4 v = *(const float4*)&Cs[r * GP + c8];
                *(float4*)(dst + (size_t)gr * 512 + c0 + c8) = v;
            }
        }
    }
}

// ------- LAYER 0, R16: R14 fp32 score path (best measured: 110-111us) ----------
#define EW0_BLOCKS 2048
#define EW0_NW (EW0_BLOCKS * 4)
__global__ __launch_bounds__(256) void fused_edge0_kernel(const int* __restrict__ off,
                                                          const int* __restrict__ csr_src,
                                                          const float* __restrict__ x,
                                                          const float* __restrict__ Wl,
                                                          const float* __restrict__ bl,
                                                          const float* __restrict__ Wr,
                                                          const float* __restrict__ br,
                                                          const float* __restrict__ att,
                                                          const float* __restrict__ bias,
                                                          __half* __restrict__ hout) {
    const int lane = threadIdx.x & 63;
    const int wglob = blockIdx.x * 4 + (threadIdx.x >> 6);
    const int loff = lane * 8;
    float4 wl00 = *(const float4*)(Wl + loff),        wl01 = *(const float4*)(Wl + loff + 4);
    float4 wl10 = *(const float4*)(Wl + 512 + loff),  wl11 = *(const float4*)(Wl + 512 + loff + 4);
    float4 wl20 = *(const float4*)(Wl + 1024 + loff), wl21 = *(const float4*)(Wl + 1024 + loff + 4);
    float4 bl0  = *(const float4*)(bl + loff),        bl1  = *(const float4*)(bl + loff + 4);
    float4 at0  = *(const float4*)(att + loff),       at1  = *(const float4*)(att + loff + 4);
    float4 wr00 = *(const float4*)(Wr + loff),        wr01 = *(const float4*)(Wr + loff + 4);
    float4 wr10 = *(const float4*)(Wr + 512 + loff),  wr11 = *(const float4*)(Wr + 512 + loff + 4);
    float4 wr20 = *(const float4*)(Wr + 1024 + loff), wr21 = *(const float4*)(Wr + 1024 + loff + 4);
    float4 br0  = *(const float4*)(br + loff),        br1  = *(const float4*)(br + loff + 4);

    for (int n = wglob; n < N_NODES; n += EW0_NW) {
        int s = off[n], e = off[n + 1];
        float xn0 = x[n * 3 + 0], xn1 = x[n * 3 + 1], xn2 = x[n * 3 + 2];
        float4 xr0, xr1;
        xr0.x = fmaf(xn0, wr00.x, fmaf(xn1, wr10.x, fmaf(xn2, wr20.x, br0.x)));
        xr0.y = fmaf(xn0, wr00.y, fmaf(xn1, wr10.y, fmaf(xn2, wr20.y, br0.y)));
        xr0.z = fmaf(xn0, wr00.z, fmaf(xn1, wr10.z, fmaf(xn2, wr20.z, br0.z)));
        xr0.w = fmaf(xn0, wr00.w, fmaf(xn1, wr10.w, fmaf(xn2, wr20.w, br0.w)));
        xr1.x = fmaf(xn0, wr01.x, fmaf(xn1, wr11.x, fmaf(xn2, wr21.x, br1.x)));
        xr1.y = fmaf(xn0, wr01.y, fmaf(xn1, wr11.y, fmaf(xn2, wr21.y, br1.y)));
        xr1.z = fmaf(xn0, wr01.z, fmaf(xn1, wr11.z, fmaf(xn2, wr21.z, br1.z)));
        xr1.w = fmaf(xn0, wr01.w, fmaf(xn1, wr11.w, fmaf(xn2, wr21.w, br1.w)));

        float mx = -1e30f, denom = 0.f;
        float a0 = 0.f, a1 = 0.f, a2 = 0.f, a3 = 0.f, a4 = 0.f, a5 = 0.f, a6 = 0.f, a7 = 0.f;

        float c0, c1, c2, n0, n1, n2;
        if (s < e) { int i0 = csr_src[s]; c0 = x[i0 * 3]; c1 = x[i0 * 3 + 1]; c2 = x[i0 * 3 + 2]; }
        if (s + 1 < e) { int i1 = csr_src[s + 1]; n0 = x[i1 * 3]; n1 = x[i1 * 3 + 1]; n2 = x[i1 * 3 + 2]; }
        for (int p = s; p < e; p++) {
            float t0, t1, t2;
            if (p + 2 < e) {
                int i2 = csr_src[p + 2];
                t0 = x[i2 * 3]; t1 = x[i2 * 3 + 1]; t2 = x[i2 * 3 + 2];
            }
            float4 v0, v1;
            v0.x = fmaf(c0, wl00.x, fmaf(c1, wl10.x, fmaf(c2, wl20.x, bl0.x)));
            v0.y = fmaf(c0, wl00.y, fmaf(c1, wl10.y, fmaf(c2, wl20.y, bl0.y)));
            v0.z = fmaf(c0, wl00.z, fmaf(c1, wl10.z, fmaf(c2, wl20.z, bl0.z)));
            v0.w = fmaf(c0, wl00.w, fmaf(c1, wl10.w, fmaf(c2, wl20.w, bl0.w)));
            v1.x = fmaf(c0, wl01.x, fmaf(c1, wl11.x, fmaf(c2, wl21.x, bl1.x)));
            v1.y = fmaf(c0, wl01.y, fmaf(c1, wl11.y, fmaf(c2, wl21.y, bl1.y)));
            v1.z = fmaf(c0, wl01.z, fmaf(c1, wl11.z, fmaf(c2, wl21.z, bl1.z)));
            v1.w = fmaf(c0, wl01.w, fmaf(c1, wl11.w, fmaf(c2, wl21.w, bl1.w)));
            float mm, s1, s2;
            mm = v0.x + xr0.x; s1 = at0.x * mm; s2 = at0.x * fabsf(mm);
            mm = v0.y + xr0.y; s1 = fmaf(at0.y, mm, s1); s2 = fmaf(at0.y, fabsf(mm), s2);
            mm = v0.z + xr0.z; s1 = fmaf(at0.z, mm, s1); s2 = fmaf(at0.z, fabsf(mm), s2);
            mm = v0.w + xr0.w; s1 = fmaf(at0.w, mm, s1); s2 = fmaf(at0.w, fabsf(mm), s2);
            mm = v1.x + xr1.x; s1 = fmaf(at1.x, mm, s1); s2 = fmaf(at1.x, fabsf(mm), s2);
            mm = v1.y + xr1.y; s1 = fmaf(at1.y, mm, s1); s2 = fmaf(at1.y, fabsf(mm), s2);
            mm = v1.z + xr1.z; s1 = fmaf(at1.z, mm, s1); s2 = fmaf(at1.z, fabsf(mm), s2);
            mm = v1.w + xr1.w; s1 = fmaf(at1.w, mm, s1); s2 = fmaf(at1.w, fabsf(mm), s2);
            float part = fmaf(A6C, s1, A4C * s2);
            part = DPP_ADD(part, 0xB1);   // quad_perm [1,0,3,2]  (xor 1)
            part = DPP_ADD(part, 0x4E);   // quad_perm [2,3,0,1]  (xor 2)
            part = DPP_ADD(part, 0x124);  // row_ror:4
            part = DPP_ADD(part, 0x128);  // row_ror:8
            float mnew = fmaxf(mx, part);
            float scale = exp2f(mx - mnew);
            float w = exp2f(part - mnew);
            denom = fmaf(denom, scale, w);
            a0 = fmaf(a0, scale, w * v0.x);
            a1 = fmaf(a1, scale, w * v0.y);
            a2 = fmaf(a2, scale, w * v0.z);
            a3 = fmaf(a3, scale, w * v0.w);
            a4 = fmaf(a4, scale, w * v1.x);
            a5 = fmaf(a5, scale, w * v1.y);
            a6 = fmaf(a6, scale, w * v1.z);
            a7 = fmaf(a7, scale, w * v1.w);
            mx = mnew;
            c0 = n0; c1 = n1; c2 = n2;
            n0 = t0; n1 = t1; n2 = t2;
        }
        float inv = denom > 0.f ? 1.f / denom : 0.f;
        a0 *= inv; a1 *= inv; a2 *= inv; a3 *= inv;
        a4 *= inv; a5 *= inv; a6 *= inv; a7 *= inv;
        a0 += __shfl_xor(a0, 16); a0 += __shfl_xor(a0, 32);
        a1 += __shfl_xor(a1, 16); a1 += __shfl_xor(a1, 32);
        a2 += __shfl_xor(a2, 16); a2 += __shfl_xor(a2, 32);
        a3 += __shfl_xor(a3, 16); a3 += __shfl_xor(a3, 32);
        a4 += __shfl_xor(a4, 16); a4 += __shfl_xor(a4, 32);
        a5 += __shfl_xor(a5, 16); a5 += __shfl_xor(a5, 32);
        a6 += __shfl_xor(a6, 16); a6 += __shfl_xor(a6, 32);
        a7 += __shfl_xor(a7, 16); a7 += __shfl_xor(a7, 32);
        if (lane < 16) {
            float4 b0 = *(const float4*)(bias + lane * 8);
            float4 b1 = *(const float4*)(bias + lane * 8 + 4);
            float o[8];
            o[0] = fmaf(0.25f, a0, b0.x); o[1] = fmaf(0.25f, a1, b0.y);
            o[2] = fmaf(0.25f, a2, b0.z); o[3] = fmaf(0.25f, a3, b0.w);
            o[4] = fmaf(0.25f, a4, b1.x); o[5] = fmaf(0.25f, a5, b1.y);
            o[6] = fmaf(0.25f, a6, b1.z); o[7] = fmaf(0.25f, a7, b1.w);
#pragma unroll
            for (int j = 0; j < 8; j++) o[j] = o[j] > 0.f ? o[j] : (exp2f(o[j] * L2E) - 1.f);
            union { __half2 h2[4]; float4 f4; } u;
            u.h2[0] = __float22half2_rn(make_float2(o[0], o[1]));
            u.h2[1] = __float22half2_rn(make_float2(o[2], o[3]));
            u.h2[2] = __float22half2_rn(make_float2(o[4], o[5]));
            u.h2[3] = __float22half2_rn(make_float2(o[6], o[7]));
            *(float4*)(hout + (size_t)n * GAT_DIM + lane * 8) = u.f4;
        }
    }
}

// ------- layers 1/2, R15 pk-fp16 (fp16-born gather; zero pack cost) --------
__global__ __launch_bounds__(256) void fused_edge_kernel(const int* __restrict__ off,
                                                         const int* __restrict__ csr_src,
                                                         const __half* __restrict__ xl,
                                                         const __half* __restrict__ xr,
                                                         const float* __restrict__ att,
                                                         const float* __restrict__ bias,
                                                         __half* __restrict__ hout) {
    int wid = threadIdx.x >> 6;
    int lane = threadIdx.x & 63;
    int n = blockIdx.x * 4 + wid;
    if (n >= N_NODES) return;
    int s = off[n], e = off[n + 1];
    const int loff = lane * 8;
    __half2 xrh[4];
    {
        float4 rxr = *(const float4*)(xr + (size_t)n * FDIM + loff);
        const __half2* xp = (const __half2*)&rxr;
        xrh[0] = xp[0]; xrh[1] = xp[1]; xrh[2] = xp[2]; xrh[3] = xp[3];
    }
    __half2 ath[4];
    {
        float4 a0r = *(const float4*)(att + loff);
        float4 a1r = *(const float4*)(att + loff + 4);
        ath[0] = __floats2half2_rn(a0r.x, a0r.y);
        ath[1] = __floats2half2_rn(a0r.z, a0r.w);
        ath[2] = __floats2half2_rn(a1r.x, a1r.y);
        ath[3] = __floats2half2_rn(a1r.z, a1r.w);
    }

    float mx = -1e30f, denom = 0.f;
    __half2 ah0 = __floats2half2_rn(0.f, 0.f);
    __half2 ah1 = ah0, ah2 = ah0, ah3 = ah0;

    float4 rcur, rnext;
    if (s < e)     rcur  = *(const float4*)(xl + (size_t)csr_src[s] * FDIM + loff);
    if (s + 1 < e) rnext = *(const float4*)(xl + (size_t)csr_src[s + 1] * FDIM + loff);
    for (int p = s; p < e; p++) {
        float4 rt;
        if (p + 2 < e) rt = *(const float4*)(xl + (size_t)csr_src[p + 2] * FDIM + loff);
        const __half2* vh = (const __half2*)&rcur;
        __half2 mm0 = __hadd2(vh[0], xrh[0]);
        __half2 mm1 = __hadd2(vh[1], xrh[1]);
        __half2 mm2 = __hadd2(vh[2], xrh[2]);
        __half2 mm3 = __hadd2(vh[3], xrh[3]);
        __half2 s1h = __hmul2(ath[0], mm0);
        s1h = __hfma2(ath[1], mm1, s1h);
        s1h = __hfma2(ath[2], mm2, s1h);
        s1h = __hfma2(ath[3], mm3, s1h);
        __half2 s2h = __hmul2(ath[0], __habs2(mm0));
        s2h = __hfma2(ath[1], __habs2(mm1), s2h);
        s2h = __hfma2(ath[2], __habs2(mm2), s2h);
        s2h = __hfma2(ath[3], __habs2(mm3), s2h);
        float s1 = __low2float(s1h) + __high2float(s1h);
        float s2 = __low2float(s2h) + __high2float(s2h);
        float part = fmaf(A6C, s1, A4C * s2);
        part = DPP_ADD(part, 0xB1);   // xor 1
        part = DPP_ADD(part, 0x4E);   // xor 2
        part = DPP_ADD(part, 0x124);  // row_ror:4
        part = DPP_ADD(part, 0x128);  // row_ror:8
        float mnew = fmaxf(mx, part);
        float scale = exp2f(mx - mnew);
        float w = exp2f(part - mnew);
        denom = fmaf(denom, scale, w);
        __half2 w2 = __float2half2_rn(w);
        __half2 sc2 = __float2half2_rn(scale);
        ah0 = __hfma2(ah0, sc2, __hmul2(w2, vh[0]));
        ah1 = __hfma2(ah1, sc2, __hmul2(w2, vh[1]));
        ah2 = __hfma2(ah2, sc2, __hmul2(w2, vh[2]));
        ah3 = __hfma2(ah3, sc2, __hmul2(w2, vh[3]));
        mx = mnew;
        rcur = rnext;
        rnext = rt;
    }
    float inv = denom > 0.f ? 1.f / denom : 0.f;
    float a0 = __low2float(ah0) * inv, a1 = __high2float(ah0) * inv;
    float a2 = __low2float(ah1) * inv, a3 = __high2float(ah1) * inv;
    float a4 = __low2float(ah2) * inv, a5 = __high2float(ah2) * inv;
    float a6 = __low2float(ah3) * inv, a7 = __high2float(ah3) * inv;
    a0 += __shfl_xor(a0, 16); a0 += __shfl_xor(a0, 32);
    a1 += __shfl_xor(a1, 16); a1 += __shfl_xor(a1, 32);
    a2 += __shfl_xor(a2, 16); a2 += __shfl_xor(a2, 32);
    a3 += __shfl_xor(a3, 16); a3 += __shfl_xor(a3, 32);
    a4 += __shfl_xor(a4, 16); a4 += __shfl_xor(a4, 32);
    a5 += __shfl_xor(a5, 16); a5 += __shfl_xor(a5, 32);
    a6 += __shfl_xor(a6, 16); a6 += __shfl_xor(a6, 32);
    a7 += __shfl_xor(a7, 16); a7 += __shfl_xor(a7, 32);
    if (lane < 16) {
        float4 b0 = *(const float4*)(bias + lane * 8);
        float4 b1 = *(const float4*)(bias + lane * 8 + 4);
        float o[8];
        o[0] = fmaf(0.25f, a0, b0.x); o[1] = fmaf(0.25f, a1, b0.y);
        o[2] = fmaf(0.25f, a2, b0.z); o[3] = fmaf(0.25f, a3, b0.w);
        o[4] = fmaf(0.25f, a4, b1.x); o[5] = fmaf(0.25f, a5, b1.y);
        o[6] = fmaf(0.25f, a6, b1.z); o[7] = fmaf(0.25f, a7, b1.w);
#pragma unroll
        for (int j = 0; j < 8; j++) o[j] = o[j] > 0.f ? o[j] : (exp2f(o[j] * L2E) - 1.f);
        union { __half2 h2[4]; float4 f4; } u;
        u.h2[0] = __float22half2_rn(make_float2(o[0], o[1]));
        u.h2[1] = __float22half2_rn(make_float2(o[2], o[3]));
        u.h2[2] = __float22half2_rn(make_float2(o[4], o[5]));
        u.h2[3] = __float22half2_rn(make_float2(o[6], o[7]));
        *(float4*)(hout + (size_t)n * GAT_DIM + lane * 8) = u.f4;
    }
}

// ---------------- mean pool over sorted batch (fp16 in, double accumulation) ------------
#define POOL_CHUNK 64
__global__ __launch_bounds__(128) void pool_kernel(const __half* __restrict__ h,
                                                   const int* __restrict__ batch,
                                                   double* __restrict__ psum,
                                                   int* __restrict__ pcnt) {
    int c = threadIdx.x;  // 0..127
    int n0 = blockIdx.x * POOL_CHUNK;
    int n1 = min(n0 + POOL_CHUNK, N_NODES);
    if (n0 >= N_NODES) return;
    double acc = 0.0;
    int cur = batch[n0];
    int cnt = 0;
    for (int n = n0; n < n1; n++) {
        int g = batch[n];
        if (g != cur) {
            atomicAdd(&psum[(size_t)cur * GAT_DIM + c], acc);
            if (c == 0) atomicAdd(&pcnt[cur], cnt);
            acc = 0.0; cnt = 0; cur = g;
        }
        acc += (double)__half2float(h[(size_t)n * GAT_DIM + c]);
        cnt++;
    }
    atomicAdd(&psum[(size_t)cur * GAT_DIM + c], acc);
    if (c == 0) atomicAdd(&pcnt[cur], cnt);
}

// ---------------- final linear: out[64,128] = g @ linW + linb ----------------
__global__ __launch_bounds__(128) void final_kernel(const double* __restrict__ psum,
                                                    const int* __restrict__ pcnt,
                                                    const float* __restrict__ linW,
                                                    const float* __restrict__ linb,
                                                    float* __restrict__ out) {
    int g = blockIdx.x;       // 0..63
    int j = threadIdx.x;      // 0..127
    __shared__ float gv[128];
    float cnt = (float)max(pcnt[g], 1);
    gv[j] = (float)(psum[(size_t)g * 128 + j] / (double)cnt);
    __syncthreads();
    float acc = 0.f;
    for (int c = 0; c < 128; c++) acc = fmaf(gv[c], linW[c * 128 + j], acc);
    out[(size_t)g * 128 + j] = acc + linb[j];
}

extern "C" void kernel_launch(void* const* d_in, const int* in_sizes, int n_in,
                              void* d_out, int out_size, void* d_ws, size_t ws_size,
                              hipStream_t stream) {
    const float* x    = (const float*)d_in[0];
    const int* eidx   = (const int*)d_in[1];
    const int* batch  = (const int*)d_in[2];
    const float* Wl[3] = {(const float*)d_in[3],  (const float*)d_in[9],  (const float*)d_in[15]};
    const float* bl[3] = {(const float*)d_in[4],  (const float*)d_in[10], (const float*)d_in[16]};
    const float* Wr[3] = {(const float*)d_in[5],  (const float*)d_in[11], (const float*)d_in[17]};
    const float* br[3] = {(const float*)d_in[6],  (const float*)d_in[12], (const float*)d_in[18]};
    const float* att[3] = {(const float*)d_in[7], (const float*)d_in[13], (const float*)d_in[19]};
    const float* bb[3] = {(const float*)d_in[8],  (const float*)d_in[14], (const float*)d_in[20]};
    const float* linW = (const float*)d_in[21];
    const float* linb = (const float*)d_in[22];
    float* out = (float*)d_out;

    const int* esrc = eidx;
    const int* edst = eidx + N_EDGES;

    // workspace carve-up (256B aligned)
    char* p = (char*)d_ws;
    auto alloc = [&](size_t bytes) { void* r = (void*)p; p += (bytes + 255) & ~(size_t)255; return r; };
    __half* xl     = (__half*)alloc((size_t)N_NODES * FDIM * 2);  // 51.2 MB (fp16)
    __half* xr     = (__half*)alloc((size_t)N_NODES * FDIM * 2);  // 51.2 MB (fp16)
    __half* hbuf   = (__half*)alloc((size_t)N_NODES * GAT_DIM * 2);// 12.8 MB (fp16)
    int*   off     = (int*)alloc((size_t)(N_NODES + 1) * 4);
    int*   csr_src = (int*)alloc((size_t)N_EDGES * 4);
    int*   bsum    = (int*)alloc((size_t)SCNB * 4);
    __half* Wt1    = (__half*)alloc((size_t)1024 * 128 * 2);
    __half* Wt2    = (__half*)alloc((size_t)1024 * 128 * 2);
    float* bc1     = (float*)alloc((size_t)1024 * 4);
    float* bc2     = (float*)alloc((size_t)1024 * 4);
    // --- contiguous zero region: deg, cursor, psum, pcnt ---
    char* zbase = p;
    int*   deg     = (int*)alloc((size_t)N_NODES * 4);
    int*   cursor  = (int*)alloc((size_t)N_NODES * 4);
    double* psum   = (double*)alloc((size_t)N_GRAPHS * GAT_DIM * 8);
    int*   pcnt    = (int*)alloc((size_t)N_GRAPHS * 4);
    size_t zbytes = (size_t)(p - zbase);

    hipMemsetAsync(zbase, 0, zbytes, stream);

    // CSR build (hierarchical scan) + merged weight prep
    deg_kernel<<<(N_EDGES + 255) / 256, 256, 0, stream>>>(edst, deg);
    scan1_kernel<<<SCNB, SCB, 0, stream>>>(deg, bsum);
    scan2_kernel<<<1, SCB, 0, stream>>>(bsum, off);
    scan3_kernel<<<SCNB, SCB, 0, stream>>>(deg, bsum, off);
    fill_kernel<<<(N_EDGES + 255) / 256, 256, 0, stream>>>(esrc, edst, off, cursor, csr_src);
    wprep_kernel<<<2048, 128, 0, stream>>>(Wl[1], Wr[1], bl[1], br[1],
                                           Wl[2], Wr[2], bl[2], br[2],
                                           Wt1, bc1, Wt2, bc2);

    const int ggrid = (N_NODES + GM - 1) / GM;   // 782 blocks, each loops 8 col tiles
    const int egrid = (N_NODES + 3) / 4;         // 4 nodes (waves) per 256-thr block

    // layer 0: fully fused (K=3 transform recomputed per edge), persistent waves
    fused_edge0_kernel<<<EW0_BLOCKS, 256, 0, stream>>>(off, csr_src, x, Wl[0], bl[0],
                                                       Wr[0], br[0], att[0], bb[0], hbuf);
    // layers 1,2
    __half* Wt[3] = {nullptr, Wt1, Wt2};
    float*  bc[3] = {nullptr, bc1, bc2};
    for (int l = 1; l < 3; l++) {
        gemm_mfma_kernel<<<ggrid, 256, 0, stream>>>(hbuf, Wt[l], bc[l], xl, xr, N_NODES);
        fused_edge_kernel<<<egrid, 256, 0, stream>>>(off, csr_src, xl, xr,
                                                     att[l], bb[l], hbuf);
    }

    pool_kernel<<<(N_NODES + POOL_CHUNK - 1) / POOL_CHUNK, 128, 0, stream>>>(hbuf, batch, psum, pcnt);
    final_kernel<<<N_GRAPHS, 128, 0, stream>>>(psum, pcnt, linW, linb, out);
}